// Round 9
// baseline (82.103 us; speedup 1.0000x reference)
//
#include <hip/hip_runtime.h>
#include <cstdint>
#include <cstddef>

typedef float v16f __attribute__((ext_vector_type(16)));
typedef short v8s  __attribute__((ext_vector_type(8)));

#define MFMA32(A,B,C) __builtin_amdgcn_mfma_f32_32x32x16_bf16((A),(B),(C),0,0,0)
#define THRU 1e-3f

__device__ __forceinline__ unsigned f2bf(float f) {
  unsigned u = __builtin_bit_cast(unsigned, f);
  u += 0x7FFFu + ((u >> 16) & 1u);
  return u >> 16;
}
__device__ __forceinline__ float bf2f(unsigned us) {
  return __builtin_bit_cast(float, us << 16);
}
__device__ __forceinline__ void gload16(const void* g, void* l) {
  __builtin_amdgcn_global_load_lds(
      (const __attribute__((address_space(1))) void*)g,
      (__attribute__((address_space(3))) void*)l, 16, 0, 0);
}

// ---------------------------------------------------------------------------
// prep: h = x @ W^T + b (f32 vector GEMM); bf16 h/m splits of x in MFMA-tiled
// layout frag[b][t=node/32][kc][lane]{16B}; EFl per-i {El,Fl}; EFh head-major
// per-j {Er,Fr}; ht transposed bf16.
// ---------------------------------------------------------------------------
__global__ __launch_bounds__(256) void gat_prep(
    const float* __restrict__ nf, const float* __restrict__ Wm,
    const float* __restrict__ bias, const float* __restrict__ aw,
    unsigned short* __restrict__ nfh, unsigned short* __restrict__ nfm,
    unsigned short* __restrict__ ht,
    float* __restrict__ EFl, float* __restrict__ EFh)
{
  __shared__ float xl[32][132];
  const int tid = threadIdx.x;
  const int row = tid & 31, g = tid >> 5;
  const int r0 = blockIdx.x * 32;          // global node row base (0..8191)
  const int b = r0 >> 11, n0 = r0 & 2047;
  const int d0 = g * 16;

  float x[16];
  {
    const float* xp = nf + (size_t)(r0 + row) * 128 + d0;
#pragma unroll
    for (int q = 0; q < 4; ++q) {
      float4 v = *(const float4*)(xp + 4 * q);
      x[4*q+0] = v.x; x[4*q+1] = v.y; x[4*q+2] = v.z; x[4*q+3] = v.w;
    }
  }
  {
    unsigned hu[16], mu[16];
#pragma unroll
    for (int q = 0; q < 16; ++q) {
      xl[row][d0 + q] = x[q];
      unsigned hb = f2bf(x[q]); float hf = bf2f(hb);
      unsigned mb = f2bf(x[q] - hf);
      hu[q] = hb; mu[q] = mb;
    }
    // tiled fragment store: (b, t=n0>>5, kc=g, lane=row)
    const size_t to = ((size_t)(b * 64 + (n0 >> 5)) * 8 + g) * 512 + row * 8;
    uint4 p0, p1;
    p0.x = hu[0] | (hu[1] << 16);  p0.y = hu[2] | (hu[3] << 16);
    p0.z = hu[4] | (hu[5] << 16);  p0.w = hu[6] | (hu[7] << 16);
    p1.x = hu[8] | (hu[9] << 16);  p1.y = hu[10] | (hu[11] << 16);
    p1.z = hu[12] | (hu[13] << 16); p1.w = hu[14] | (hu[15] << 16);
    *(uint4*)(nfh + to) = p0; *(uint4*)(nfh + to + 256) = p1;
    p0.x = mu[0] | (mu[1] << 16);  p0.y = mu[2] | (mu[3] << 16);
    p0.z = mu[4] | (mu[5] << 16);  p0.w = mu[6] | (mu[7] << 16);
    p1.x = mu[8] | (mu[9] << 16);  p1.y = mu[10] | (mu[11] << 16);
    p1.z = mu[12] | (mu[13] << 16); p1.w = mu[14] | (mu[15] << 16);
    *(uint4*)(nfm + to) = p0; *(uint4*)(nfm + to + 256) = p1;
  }
  __syncthreads();

  float acc[16];
  const int ob = g * 16;
#pragma unroll
  for (int o = 0; o < 16; ++o) acc[o] = bias[ob + o];
  for (int dd = 0; dd < 128; dd += 4) {
    float4 xq = *(const float4*)&xl[row][dd];
#pragma unroll
    for (int o = 0; o < 16; ++o) {
      float4 wq = *(const float4*)(Wm + (size_t)(ob + o) * 128 + dd);
      acc[o] = fmaf(xq.x, wq.x, acc[o]);
      acc[o] = fmaf(xq.y, wq.y, acc[o]);
      acc[o] = fmaf(xq.z, wq.z, acc[o]);
      acc[o] = fmaf(xq.w, wq.w, acc[o]);
    }
  }
#pragma unroll
  for (int o = 0; o < 16; ++o)
    ht[((size_t)b * 128 + ob + o) * 2048 + n0 + row] = (unsigned short)f2bf(acc[o]);

  const int hh = g >> 1, cb = (g & 1) * 16;
  float sl = 0.f, sr = 0.f;
#pragma unroll
  for (int o = 0; o < 16; ++o) {
    sl = fmaf(acc[o], aw[hh * 64 + cb + o], sl);
    sr = fmaf(acc[o], aw[hh * 64 + 32 + cb + o], sr);
  }
  sl += __shfl_xor(sl, 32, 64);
  sr += __shfl_xor(sr, 32, 64);
  if (!(g & 1)) {
    const float L2E = 1.4426950408889634f;
    float El = exp2f(sl * L2E), Fl = exp2f(sl * (0.3f * L2E));
    float Er = exp2f(sr * L2E), Fr = exp2f(sr * (0.3f * L2E));
    size_t nn = (size_t)(r0 + row);
    EFl[nn * 8 + hh]     = El;
    EFl[nn * 8 + 4 + hh] = Fl;
    const size_t eo = ((size_t)(b * 4 + hh) * 2048 + (n0 + row)) * 2;
    EFh[eo]     = Er;
    EFh[eo + 1] = Fr;
  }
}

// ---------------------------------------------------------------------------
// mask: S = 3-pass split-bf16 (hh+hm+mh) from TILED fragments (coalesced 1KB
// loads). Lanes with any |S|<THR recompute the exact f64 dot INLINE and patch
// their sign bit before the single mask-word store. Zero atomics, no list.
// mask layout: u32 mask[b][j>>5][i], bit = j&31.
// ---------------------------------------------------------------------------
__global__ __launch_bounds__(256) void gat_mask(
    const unsigned short* __restrict__ nfh, const unsigned short* __restrict__ nfm,
    const float* __restrict__ nf, unsigned* __restrict__ mask)
{
  const int tid = threadIdx.x, lane = tid & 63;
  const int li = lane & 31, hi = lane >> 5;
  const int blk = blockIdx.x;
  const int jb = blk & 31, t = blk >> 5;
  const int ib = t & 15, b = t >> 4;
  const int i0 = ib * 128 + (tid >> 6) * 32;
  const int j0 = jb * 64;

  const size_t lbyte = (size_t)lane * 8;
  const size_t tiB  = ((size_t)(b * 64 + (i0 >> 5)) * 8) * 512 + lbyte;
  const size_t tjA0 = ((size_t)(b * 64 + (j0 >> 5)) * 8) * 512 + lbyte;
  const size_t tjA1 = tjA0 + 4096;

  v8s BH[8], BM[8];
#pragma unroll
  for (int kc = 0; kc < 8; ++kc) {
    BH[kc] = *(const v8s*)(nfh + tiB + kc * 512);
    BM[kc] = *(const v8s*)(nfm + tiB + kc * 512);
  }

  v16f S0, S1;
#pragma unroll
  for (int r = 0; r < 16; ++r) { S0[r] = 0.f; S1[r] = 0.f; }
#pragma unroll
  for (int kc = 0; kc < 8; ++kc) {
    v8s A0h = *(const v8s*)(nfh + tjA0 + kc * 512);
    v8s A1h = *(const v8s*)(nfh + tjA1 + kc * 512);
    v8s A0m = *(const v8s*)(nfm + tjA0 + kc * 512);
    v8s A1m = *(const v8s*)(nfm + tjA1 + kc * 512);
    S0 = MFMA32(A0h, BH[kc], S0);
    S1 = MFMA32(A1h, BH[kc], S1);
    S0 = MFMA32(A0h, BM[kc], S0);
    S1 = MFMA32(A1h, BM[kc], S1);
    S0 = MFMA32(A0m, BH[kc], S0);
    S1 = MFMA32(A1m, BH[kc], S1);
  }

  // sign bits + min|S|
  unsigned u0 = 0, u1 = 0;
  float mn = 1e30f;
  const int sh = hi * 4;
#pragma unroll
  for (int r = 0; r < 16; ++r) {
    const int jlc = (r & 3) + 8 * (r >> 2);
    const unsigned bit = (1u << jlc) << sh;
    if (S0[r] > 0.f) u0 |= bit;
    if (S1[r] > 0.f) u1 |= bit;
    mn = fminf(mn, fabsf(S0[r]));
    mn = fminf(mn, fabsf(S1[r]));
  }

  // rare inline exact fix (divergent; ~1-2K entries total over the grid)
  if (mn < THRU) {
    const float* xi = nf + ((size_t)b * 2048 + i0 + li) * 128;
#pragma unroll
    for (int sub = 0; sub < 2; ++sub) {
#pragma unroll
      for (int r = 0; r < 16; ++r) {
        const float s = sub ? S1[r] : S0[r];
        if (fabsf(s) < THRU) {
          const int jlc = (r & 3) + 8 * (r >> 2);
          const int j = j0 + sub * 32 + jlc + 4 * hi;
          const float* xj = nf + ((size_t)b * 2048 + j) * 128;
          double a = 0.0;
          for (int k = 0; k < 128; k += 2) {
            a = fma((double)xi[k],     (double)xj[k],     a);
            a = fma((double)xi[k + 1], (double)xj[k + 1], a);
          }
          const unsigned bit = (1u << jlc) << sh;
          if (sub == 0) u0 = (a > 0.0) ? (u0 | bit) : (u0 & ~bit);
          else          u1 = (a > 0.0) ? (u1 | bit) : (u1 & ~bit);
        }
      }
    }
  }

  unsigned f0 = u0 | (unsigned)__shfl_xor((int)u0, 32, 64);
  unsigned f1 = u1 | (unsigned)__shfl_xor((int)u1, 32, 64);
  if (hi == 0) {
    mask[(size_t)(b * 64 + jb * 2)     * 2048 + i0 + li] = f0;
    mask[(size_t)(b * 64 + jb * 2 + 1) * 2048 + i0 + li] = f1;
  }
}

// ---------------------------------------------------------------------------
// attn: block = 32 i x 1 head x full j; 4 waves split j (512 each) with
// WAVE-PRIVATE double-buffered staging (V 4KB + EF 512B per buf) — zero
// barriers in the main loop; counted s_waitcnt vmcnt(5) pipelines staging
// under compute. End: LDS combine of 4 j-partials, divide by den, write out.
// LDS: 4 waves x 2 bufs x 4608B = 36864.
// ---------------------------------------------------------------------------
__global__ __launch_bounds__(256, 2) void gat_attn(
    const unsigned short* __restrict__ ht, const float* __restrict__ EFl,
    const float* __restrict__ EFh, const unsigned* __restrict__ mask,
    float* __restrict__ out)
{
  __shared__ __align__(16) char sm[36864];
  const int tid = threadIdx.x, lane = tid & 63, wv = tid >> 6;
  const int li = lane & 31, hi = lane >> 5;

  // XCD-aware decode: blocks sharing (b,h) land on one XCD.
  const int blk = blockIdx.x;
  const int ig = (blk >> 3) & 63;
  const int combo = (blk & 7) * 2 + (blk >> 9);   // 0..15
  const int b = combo >> 2, h = combo & 3;

  const size_t nb = (size_t)b * 2048;
  const int i0 = ig * 32;
  const int j0w = wv * 512;
  char* mybase = sm + wv * 9216;

  const float EL = EFl[(nb + i0 + li) * 8 + h];
  const float FL = EFl[(nb + i0 + li) * 8 + 4 + h];

  unsigned mw[16];
#pragma unroll
  for (int q = 0; q < 16; ++q)
    mw[q] = mask[(size_t)(b * 64 + wv * 16 + q) * 2048 + i0 + li] >> (hi * 4);

  // fence ALL register loads so staging vmcnt counts are exact
  asm volatile("s_waitcnt vmcnt(0)" ::: "memory");
  __builtin_amdgcn_sched_barrier(0);

  const int vrow = lane >> 3, vgs = lane & 7;
  auto STAGE = [&](int h0, int p) {   // exactly 5 vmem instructions
    const int jbase = j0w + (h0 << 6);
    const size_t srow = (size_t)(b * 128 + h * 32) * 2048 + jbase;
#pragma unroll
    for (int q = 0; q < 4; ++q) {
      const int row = q * 8 + vrow;
      gload16((const char*)(ht + srow + (size_t)row * 2048 + ((vgs ^ (row & 7)) << 3)),
              mybase + p * 4608 + q * 1024);
    }
    if (lane < 32)
      gload16((const char*)EFh + ((size_t)(b * 4 + h) * 2048 + jbase) * 8 + lane * 16,
              mybase + p * 4608 + 4096);
  };

  STAGE(0, 0);

  v16f acc;
#pragma unroll
  for (int r = 0; r < 16; ++r) acc[r] = 0.f;
  float den = 0.f;

#pragma unroll
  for (int h0 = 0; h0 < 8; ++h0) {
    const int p = h0 & 1;
    if (h0 < 7) {
      STAGE(h0 + 1, p ^ 1);
      asm volatile("s_waitcnt vmcnt(5)" ::: "memory");   // drain stage(h0) only
    } else {
      asm volatile("s_waitcnt vmcnt(0)" ::: "memory");
    }
    __builtin_amdgcn_sched_barrier(0);

    const char* base = mybase + p * 4608;
#pragma unroll
    for (int it2 = 0; it2 < 2; ++it2) {
      const unsigned mh = mw[h0 * 2 + it2];
      const char* Eb = base + 4096 + (it2 << 8);
      unsigned pw[8];
#pragma unroll
      for (int rp = 0; rp < 8; ++rp) {
        const int r0 = 2 * rp;
        const int jl0c = (r0 & 3) + 8 * (r0 >> 2);
        const int off = (jl0c + 4 * hi) * 8;
        float2 e0 = *(const float2*)(Eb + off);       // {Er,Fr} node jl0c
        float2 e1 = *(const float2*)(Eb + off + 8);   // node jl0c+1
        const bool m0 = (mh >> jl0c) & 1;
        const bool m1 = (mh >> (jl0c + 1)) & 1;
        float w0 = fmaxf(e0.x * EL, e0.y * FL); w0 = m0 ? w0 : 0.f;
        float w1 = fmaxf(e1.x * EL, e1.y * FL); w1 = m1 ? w1 : 0.f;
        den += w0 + w1;
        asm("v_cvt_pk_bf16_f32 %0, %1, %2" : "=v"(pw[rp]) : "v"(w0), "v"(w1));
      }
      auto q0 = __builtin_amdgcn_permlane32_swap((int)pw[0], (int)pw[2], false, false);
      auto q1 = __builtin_amdgcn_permlane32_swap((int)pw[1], (int)pw[3], false, false);
      auto q2 = __builtin_amdgcn_permlane32_swap((int)pw[4], (int)pw[6], false, false);
      auto q3 = __builtin_amdgcn_permlane32_swap((int)pw[5], (int)pw[7], false, false);
      uint4 c0, c1;
      c0.x = (unsigned)q0[0]; c0.y = (unsigned)q1[0];
      c0.z = (unsigned)q0[1]; c0.w = (unsigned)q1[1];
      c1.x = (unsigned)q2[0]; c1.y = (unsigned)q3[0];
      c1.z = (unsigned)q2[1]; c1.w = (unsigned)q3[1];
      v8s P0 = __builtin_bit_cast(v8s, c0);
      v8s P1 = __builtin_bit_cast(v8s, c1);
      const char* vr = base + li * 128;
      const int cx = li & 7;
      v8s V0 = *(const v8s*)(vr + ((((it2 << 2) + hi) ^ cx) << 4));
      v8s V1 = *(const v8s*)(vr + ((((it2 << 2) + 2 + hi) ^ cx) << 4));
      acc = MFMA32(P0, V0, acc);
      acc = MFMA32(P1, V1, acc);
    }
  }

  // ---- cross-wave combine (reuse sm), divide, direct output ----
  __syncthreads();
  if (wv) {
    float* dst = (float*)sm + (size_t)(wv - 1) * 1088 + lane * 17;
#pragma unroll
    for (int r = 0; r < 16; ++r) dst[r] = acc[r];
    dst[16] = den;
  }
  __syncthreads();
  if (wv == 0) {
#pragma unroll
    for (int w = 0; w < 3; ++w) {
      const float* src = (const float*)sm + (size_t)w * 1088 + lane * 17;
#pragma unroll
      for (int r = 0; r < 16; ++r) acc[r] += src[r];
      den += src[16];
    }
    den += __shfl_xor(den, 32, 64);
    float* dl = (float*)sm + 3 * 1088;      // 32-entry den broadcast table
    if (lane < 32) dl[li] = den;
    asm volatile("s_waitcnt lgkmcnt(0)" ::: "memory");
    __builtin_amdgcn_sched_barrier(0);
    const size_t ob = (nb + i0) * 128 + h * 32 + li;
#pragma unroll
    for (int r = 0; r < 16; ++r) {
      const int il = (r & 3) + 8 * (r >> 2) + 4 * hi;
      out[ob + (size_t)il * 128] = acc[r] / dl[il];
    }
  }
}

// ---------------------------------------------------------------------------
extern "C" void kernel_launch(void* const* d_in, const int* in_sizes, int n_in,
                              void* d_out, int out_size, void* d_ws, size_t ws_size,
                              hipStream_t stream) {
  const float* nf   = (const float*)d_in[0];
  const float* Wm   = (const float*)d_in[1];
  const float* bias = (const float*)d_in[2];
  const float* aw   = (const float*)d_in[3];
  float* out = (float*)d_out;
  char* ws = (char*)d_ws;

  // layout (bytes)
  unsigned short* nfh = (unsigned short*)(ws);             // 2,097,152 (tiled)
  unsigned short* nfm = (unsigned short*)(ws + 2097152);   // 2,097,152 (tiled)
  unsigned short* ht  = (unsigned short*)(ws + 4194304);   // 2,097,152
  float*    EFl  = (float*)(ws + 6291456);                 //   262,144
  float*    EFh  = (float*)(ws + 6553600);                 //   262,144
  unsigned* mask = (unsigned*)(ws + 6815744);              // 2,097,152

  gat_prep<<<256, 256, 0, stream>>>(nf, Wm, bias, aw, nfh, nfm, ht, EFl, EFh);
  gat_mask<<<2048, 256, 0, stream>>>(nfh, nfm, nf, mask);
  gat_attn<<<1024, 256, 0, stream>>>(ht, EFl, EFh, mask, out);
}